// Round 1
// baseline (1303.934 us; speedup 1.0000x reference)
//
#include <hip/hip_runtime.h>

// Problem constants (fixed by the reference)
#define NUu 100000
#define NIi 50000
#define NEe 2000000
// D = DIN = 64, NB = 2, NC = 5

// out[n,c] = c[n] * sum_k feat[n,k] * W[k,c]   (feat [N,64], W [64,64])
__global__ __launch_bounds__(256) void gemm64_scale(
    const float* __restrict__ feat, const float* __restrict__ W,
    const float* __restrict__ cvec, float* __restrict__ out, int N)
{
    __shared__ float Wl[64 * 64];      // 16 KB
    __shared__ float rows[16][64];     // 4 KB
    const int tid = threadIdx.x;
    for (int i = tid; i < 4096; i += 256) Wl[i] = W[i];
    const int r0 = blockIdx.x * 16;
    for (int i = tid; i < 16 * 64; i += 256) {
        int r = r0 + (i >> 6);
        rows[i >> 6][i & 63] = (r < N) ? feat[r * 64 + (i & 63)] : 0.f;
    }
    __syncthreads();
    const int col = tid & 63;
    const int rq  = tid >> 6;          // wave id: 0..3 (uniform per wave)
    for (int rr = rq; rr < 16; rr += 4) {
        int r = r0 + rr;
        if (r >= N) continue;
        float s = 0.f;
        #pragma unroll
        for (int k = 0; k < 64; ++k)
            s = fmaf(rows[rr][k], Wl[k * 64 + col], s);  // rows: broadcast, Wl: conflict-free
        out[r * 64 + col] = s * cvec[r];
    }
}

// acc[sct[e], :] += msg[gth[e], :]   one wave per edge, grid-stride
__global__ __launch_bounds__(256) void scatter_add(
    const float* __restrict__ msg, const int* __restrict__ gth,
    const int* __restrict__ sct, float* __restrict__ acc, int E)
{
    const int lane   = threadIdx.x & 63;
    const int wid    = blockIdx.x * 4 + (threadIdx.x >> 6);
    const int nwaves = gridDim.x * 4;
    for (int e = wid; e < E; e += nwaves) {
        int g = gth[e];
        int s = sct[e];
        atomicAdd(&acc[s * 64 + lane], msg[g * 64 + lane]);
    }
}

// h[i,:] *= c[i]
__global__ __launch_bounds__(256) void scale_rows(
    float* __restrict__ h, const float* __restrict__ cvec, int N)
{
    int i = blockIdx.x * 256 + threadIdx.x;
    if (i < N * 64) h[i] *= cvec[i >> 6];
}

// hb[n, b, :] = sum_k h[n,k] * P[b,k,:]    (P: [2,64,64], both bases in LDS)
__global__ __launch_bounds__(256) void basis_proj(
    const float* __restrict__ h, const float* __restrict__ P,
    float* __restrict__ hb, int N)
{
    __shared__ float Pl[2 * 64 * 64];  // 32 KB
    __shared__ float rows[8][64];      // 2 KB
    const int tid = threadIdx.x;
    for (int i = tid; i < 8192; i += 256) Pl[i] = P[i];
    const int r0 = blockIdx.x * 8;
    for (int i = tid; i < 8 * 64; i += 256) {
        int r = r0 + (i >> 6);
        rows[i >> 6][i & 63] = (r < N) ? h[r * 64 + (i & 63)] : 0.f;
    }
    __syncthreads();
    const int col = tid & 63;
    const int b   = (tid >> 6) & 1;    // uniform per wave
    const int rh  = tid >> 7;          // 0..1, uniform per wave
    for (int rr = rh; rr < 8; rr += 2) {
        int r = r0 + rr;
        if (r >= N) continue;
        float s = 0.f;
        #pragma unroll
        for (int k = 0; k < 64; ++k)
            s = fmaf(rows[rr][k], Pl[b * 4096 + k * 64 + col], s);
        hb[r * 128 + b * 64 + col] = s;
    }
}

// out[e,c] = sum_b (hb[src[e],b,:] . hi[dst[e],:]) * Wc[c,b]
__global__ __launch_bounds__(256) void edge_out(
    const float* __restrict__ hb, const float* __restrict__ hi,
    const int* __restrict__ src, const int* __restrict__ dst,
    const float* __restrict__ Wc, float* __restrict__ out, int E)
{
    const int lane   = threadIdx.x & 63;
    const int wid    = blockIdx.x * 4 + (threadIdx.x >> 6);
    const int nwaves = gridDim.x * 4;
    float wc0 = 0.f, wc1 = 0.f;
    if (lane < 5) { wc0 = Wc[lane * 2 + 0]; wc1 = Wc[lane * 2 + 1]; }
    for (int e = wid; e < E; e += nwaves) {
        int s = src[e];
        int d = dst[e];
        float hv = hi[d * 64 + lane];
        float p0 = hb[s * 128 + lane]      * hv;
        float p1 = hb[s * 128 + 64 + lane] * hv;
        #pragma unroll
        for (int m = 1; m < 64; m <<= 1) {
            p0 += __shfl_xor(p0, m, 64);
            p1 += __shfl_xor(p1, m, 64);
        }
        if (lane < 5) out[e * 5 + lane] = p0 * wc0 + p1 * wc1;
    }
}

extern "C" void kernel_launch(void* const* d_in, const int* in_sizes, int n_in,
                              void* d_out, int out_size, void* d_ws, size_t ws_size,
                              hipStream_t stream) {
    const float* ufeat  = (const float*)d_in[0];
    const float* ifeat  = (const float*)d_in[1];
    const float* c_u    = (const float*)d_in[2];
    const float* c_i    = (const float*)d_in[3];
    const float* W_user = (const float*)d_in[4];
    const float* W_item = (const float*)d_in[5];
    const float* P      = (const float*)d_in[6];
    const float* Wc     = (const float*)d_in[7];
    const int*   src    = (const int*)d_in[8];
    const int*   dst    = (const int*)d_in[9];
    float* out = (float*)d_out;
    float* ws  = (float*)d_ws;

    // Workspace layout (floats). msg_u / msg_i alias the hu_b region: they are
    // dead before basis_proj writes hu_b.
    float* h_item = ws;                       // NI*64  = 3,200,000
    float* h_user = ws + 3200000;             // NU*64  = 6,400,000
    float* hu_b   = ws + 9600000;             // NU*128 = 12,800,000
    float* msg_u  = hu_b;                     // NU*64 (alias, dead before hu_b)
    float* msg_i  = hu_b + 6400000;           // NI*64 (alias, dead before hu_b)
    // total: 22,400,000 floats = 89.6 MB

    // Accumulators must be zeroed every call (d_ws poisoned once, never restored)
    hipMemsetAsync(ws, 0, (size_t)9600000 * sizeof(float), stream);

    gemm64_scale<<<(NUu + 15) / 16, 256, 0, stream>>>(ufeat, W_user, c_u, msg_u, NUu);
    scatter_add<<<2048, 256, 0, stream>>>(msg_u, src, dst, h_item, NEe);
    scale_rows<<<(NIi * 64 + 255) / 256, 256, 0, stream>>>(h_item, c_i, NIi);

    gemm64_scale<<<(NIi + 15) / 16, 256, 0, stream>>>(ifeat, W_item, c_i, msg_i, NIi);
    scatter_add<<<2048, 256, 0, stream>>>(msg_i, dst, src, h_user, NEe);
    scale_rows<<<(NUu * 64 + 255) / 256, 256, 0, stream>>>(h_user, c_u, NUu);

    basis_proj<<<(NUu + 7) / 8, 256, 0, stream>>>(h_user, P, hu_b, NUu);
    edge_out<<<2048, 256, 0, stream>>>(hu_b, h_item, src, dst, Wc, out, NEe);
}